// Round 15
// baseline (63.162 us; speedup 1.0000x reference)
//
#include <hip/hip_runtime.h>
#include <hip/hip_fp16.h>

// RoIAlign dense (11x11 bilinear) + 3x3/s2 max pool -> [K=2048, C=256, 5, 5]
// features: [B=4, C=256, H=100, W=100] f32 (NCHW), rois: [K,5] f32
//
// Ladder: R5 42 main (f32 scalar) -> R8 ~34 (bf16 pair dword loads) ->
// R14 ~31 (f16 half2: no unpack, packed lerps; total 42.5 BEST).
// Calibration R8<->R9: same bytes, 2x VMEM instrs = +6.7us -> per-instruction
// cost dominates now that VALU is packed. R15: uint2 loads (2 pairs = 4
// channels per lane) halve VMEM instructions; one wave covers all 128 pairs;
// 2 waves per roi split by row group (R12-verified mapping, row 4 dup):
//   rg0: rows 0-4 -> ph0,ph1   rg1: rows 4-10 -> ph2,ph3,ph4
// Stage = u32 half2-pairs (12.8 KB), written per-ph (bounded VGPR), one
// barrier, branchless lo/hi unpack on the coalesced copy-out.

constexpr int Bn = 4, Cn = 256, Hn = 100, Wn = 100;
constexpr int HWn = Hn * Wn;
constexpr int PAIRS = Cn / 2;            // 128 channel pairs
constexpr float SCALE = 0.0625f;

__device__ __forceinline__ unsigned int hpack(float a, float b) {
    // RTNE f32->f16, pack (a -> low16, b -> high16)
    const __half2 h = __halves2half2(__float2half_rn(a), __float2half_rn(b));
    return *reinterpret_cast<const unsigned int*>(&h);
}
__device__ __forceinline__ __half2 u2h(unsigned int u) {
    return *reinterpret_cast<__half2*>(&u);
}
__device__ __forceinline__ unsigned int h2u(__half2 h) {
    return *reinterpret_cast<unsigned int*>(&h);
}
__device__ __forceinline__ __half2 hmax2(__half2 a, __half2 b) {
    // ROCm 7.2 has no __hmax2; emit the VOP3P packed max directly.
    unsigned int ur;
    asm("v_pk_max_f16 %0, %1, %2" : "=v"(ur) : "v"(h2u(a)), "v"(h2u(b)));
    return u2h(ur);
}

// ------- Kernel 1: NCHW f32 -> NHWC f16 (c, c+128)-pair (u32) transpose -------
// blockIdx.y covers 32 pairs: pairs p0..p0+31 = channels {p0+r, p0+r+128}.
__global__ __launch_bounds__(256)
void nchw_to_nhwc_f16(const float* __restrict__ in, unsigned int* __restrict__ out)
{
    __shared__ float tile[64][65];           // rows 0..31: ch p0+r; 32..63: ch p0+128+(r-32)
    const int s0 = blockIdx.x * 64;
    const int p0 = blockIdx.y * 32;          // pair-tile base (0,32,64,96)
    const int b  = blockIdx.z;
    const int t  = threadIdx.x;

    {   // load: thread -> tile row, 4 consecutive spatial (dwordx4)
        const int cl = t >> 4;               // 0..15
        const int s4 = (t & 15) * 4;         // 0..60
        const float* ip = in + (size_t)b * Cn * HWn + s0;
#pragma unroll
        for (int pass = 0; pass < 4; ++pass) {
            const int r  = pass * 16 + cl;   // tile row 0..63
            const int ch = (pass < 2) ? (p0 + r) : (p0 + 96 + r);  // +128 for hi half
            if (s0 + s4 + 3 < HWn) {
                const float4 v = *(const float4*)(ip + (size_t)ch * HWn + s4);
                tile[r][s4 + 0] = v.x; tile[r][s4 + 1] = v.y;
                tile[r][s4 + 2] = v.z; tile[r][s4 + 3] = v.w;
            } else {
#pragma unroll
                for (int i = 0; i < 4; ++i)
                    tile[r][s4 + i] = (s0 + s4 + i < HWn) ? ip[(size_t)ch * HWn + s4 + i] : 0.0f;
            }
        }
    }
    __syncthreads();
    {   // store: thread -> spatial s, uint2 = pairs (p0+li, p0+li+1)
        const int s = t >> 2;                // 0..63
        const int q = t & 3;
        if (s0 + s < HWn) {
            unsigned int* op = out + ((size_t)b * HWn + (s0 + s)) * PAIRS + p0;
#pragma unroll
            for (int i = 0; i < 4; ++i) {
                const int li = q * 2 + i * 8;            // even, 0..30
                uint2 v;
                v.x = hpack(tile[li    ][s], tile[li + 32][s]);  // pair p0+li
                v.y = hpack(tile[li + 1][s], tile[li + 33][s]);  // pair p0+li+1
                *(uint2*)(op + li) = v;
            }
        }
    }
}

// ------- Kernel 2: RoIAlign+pool, lane = 2 channel pairs (uint2 loads) -------
// 128-thread block = 1 roi; wave = row group. Each lane handles pairs
// (2*lane, 2*lane+1) = channels {2l, 2l+1, 2l+128, 2l+129}.
__global__ __launch_bounds__(128)
void roipool_u2(const __half2* __restrict__ f, const float* __restrict__ rois,
                float* __restrict__ out)
{
    __shared__ unsigned int stage[PAIRS * 25];   // 12.8 KB, half2 per (pair, ph, pw)
    const int tid  = threadIdx.x;
    const int rg   = tid >> 6;                   // row group (wave-uniform)
    const int lane = tid & 63;
    const int k    = blockIdx.x;

    const float x1 = rois[k * 5 + 1] * SCALE;
    const float y1 = rois[k * 5 + 2] * SCALE;
    const float x2 = rois[k * 5 + 3] * SCALE;
    const float y2 = rois[k * 5 + 4] * SCALE;
    const int   b  = __builtin_amdgcn_readfirstlane((int)rois[k * 5 + 0]);

    const __half2* fb = f + (size_t)b * HWn * PAIRS;

    // per-roi x-tap metadata: element offsets as SGPRs, weights as half2
    int     xo0[11], xo1[11];
    __half2 wxh[11];
#pragma unroll
    for (int j = 0; j < 11; ++j) {
        const float xs  = x1 + (x2 - x1) * ((float)j * 0.1f);
        const float x0f = floorf(xs);
        wxh[j] = __float2half2_rn(xs - x0f);     // weight from UNCLIPPED coord
        const int x0i = (int)x0f;
        xo0[j] = __builtin_amdgcn_readfirstlane(min(max(x0i,     0), Wn - 1)) * PAIRS;
        xo1[j] = __builtin_amdgcn_readfirstlane(min(max(x0i + 1, 0), Wn - 1)) * PAIRS;
    }

    // one dense sample row gy -> 5 x-window maxes for pairs 2l (d0) and 2l+1 (d1)
    auto dorow = [&](int gy, __half2 (&d0)[5], __half2 (&d1)[5]) {
        const float ys  = y1 + (y2 - y1) * ((float)gy * 0.1f);
        const float y0f = floorf(ys);
        const __half2 wyh = __float2half2_rn(ys - y0f);
        const int   y0i = (int)y0f;
        const int r0 = __builtin_amdgcn_readfirstlane(min(max(y0i,     0), Hn - 1));
        const int r1 = __builtin_amdgcn_readfirstlane(min(max(y0i + 1, 0), Hn - 1));
        const __half2* rp0 = fb + (size_t)(r0 * Wn) * PAIRS;   // uniform row ptrs
        const __half2* rp1 = fb + (size_t)(r1 * Wn) * PAIRS;
#pragma unroll
        for (int j = 0; j < 11; ++j) {
            // 4 taps x uint2: 8B/lane, 64 lanes cover all 128 pairs
            const uint2 a00 = *((const uint2*)(rp0 + xo0[j]) + lane);
            const uint2 a01 = *((const uint2*)(rp0 + xo1[j]) + lane);
            const uint2 a10 = *((const uint2*)(rp1 + xo0[j]) + lane);
            const uint2 a11 = *((const uint2*)(rp1 + xo1[j]) + lane);
            __half2 s0, s1;
            {   // pair 2*lane
                const __half2 t00 = u2h(a00.x), t01 = u2h(a01.x);
                const __half2 t10 = u2h(a10.x), t11 = u2h(a11.x);
                const __half2 X0 = __hfma2(wxh[j], __hsub2(t01, t00), t00);
                const __half2 X1 = __hfma2(wxh[j], __hsub2(t11, t10), t10);
                s0 = __hfma2(wyh, __hsub2(X1, X0), X0);
            }
            {   // pair 2*lane+1
                const __half2 t00 = u2h(a00.y), t01 = u2h(a01.y);
                const __half2 t10 = u2h(a10.y), t11 = u2h(a11.y);
                const __half2 X0 = __hfma2(wxh[j], __hsub2(t01, t00), t00);
                const __half2 X1 = __hfma2(wxh[j], __hsub2(t11, t10), t10);
                s1 = __hfma2(wyh, __hsub2(X1, X0), X0);
            }
            if (j == 0)      { d0[0] = s0; d1[0] = s1; }
            else if (j & 1)  { d0[j >> 1] = hmax2(d0[j >> 1], s0);
                               d1[j >> 1] = hmax2(d1[j >> 1], s1); }
            else {
                d0[(j >> 1) - 1] = hmax2(d0[(j >> 1) - 1], s0);
                d1[(j >> 1) - 1] = hmax2(d1[(j >> 1) - 1], s1);
                if (j < 10) { d0[j >> 1] = s0; d1[j >> 1] = s1; }
            }
        }
    };

    // pooled ph row = max of three dense rows; write straight to LDS stage
    auto wrph = [&](int ph, const __half2 (&a0)[5], const __half2 (&b0)[5], const __half2 (&c0)[5],
                            const __half2 (&a1)[5], const __half2 (&b1)[5], const __half2 (&c1)[5]) {
        unsigned int* s0 = &stage[(2 * lane + 0) * 25 + ph * 5];
        unsigned int* s1 = &stage[(2 * lane + 1) * 25 + ph * 5];
#pragma unroll
        for (int pw = 0; pw < 5; ++pw) {
            s0[pw] = h2u(hmax2(hmax2(a0[pw], b0[pw]), c0[pw]));
            s1[pw] = h2u(hmax2(hmax2(a1[pw], b1[pw]), c1[pw]));
        }
    };

    __half2 A0[5], A1[5], B0[5], B1[5], C0[5], C1[5];
    if (rg == 0) {                            // rows 0..4 -> ph0 (0,1,2), ph1 (2,3,4)
        dorow(0, A0, A1); dorow(1, B0, B1); dorow(2, C0, C1);
        wrph(0, A0, B0, C0, A1, B1, C1);
        dorow(3, A0, A1); dorow(4, B0, B1);
        wrph(1, C0, A0, B0, C1, A1, B1);
    } else {                                  // rows 4..10 -> ph2 (4,5,6), ph3 (6,7,8), ph4 (8,9,10)
        dorow(4, A0, A1); dorow(5, B0, B1); dorow(6, C0, C1);
        wrph(2, A0, B0, C0, A1, B1, C1);
        dorow(7, A0, A1); dorow(8, B0, B1);
        wrph(3, C0, A0, B0, C1, A1, B1);
        dorow(9, C0, C1); dorow(10, A0, A1);
        wrph(4, B0, C0, A0, B1, C1, A1);
    }

    __syncthreads();

    // coalesced copy-out: 6400 floats = 50 iters x 128 threads, branchless lo/hi
    float* ob = out + (size_t)k * (Cn * 25);
#pragma unroll
    for (int i = 0; i < 50; ++i) {
        const int idx = i * 128 + tid;        // 0..6399 = c*25 + (ph*5+pw)
        const int c   = idx / 25;             // 0..255 (const-div -> magic mul)
        const int sub = idx - c * 25;
        const __half2 h = u2h(stage[(c & 127) * 25 + sub]);
        ob[idx] = (c < 128) ? __low2float(h) : __high2float(h);
    }
}

// ------------- Fallback (reads NCHW directly) if workspace too small -------------
__global__ __launch_bounds__(256)
void roialign_pool_fallback(const float* __restrict__ feats,
                            const float* __restrict__ rois,
                            float* __restrict__ out)
{
    __shared__ float smem[4][2][128];
    const int k    = blockIdx.x;
    const int tid  = threadIdx.x;
    const int wid  = tid >> 6;
    const int lane = tid & 63;

    const float x1 = rois[k * 5 + 1] * SCALE;
    const float y1 = rois[k * 5 + 2] * SCALE;
    const float x2 = rois[k * 5 + 3] * SCALE;
    const float y2 = rois[k * 5 + 4] * SCALE;
    const int   b  = (int)rois[k * 5 + 0];

    const int  p1   = 64 + lane;
    const bool act1 = (p1 < 121);
    int   o00[2], o01[2], o10[2], o11[2];
    float w00[2], w01[2], w10[2], w11[2];
#pragma unroll
    for (int r = 0; r < 2; ++r) {
        const int p  = (r == 0) ? lane : (act1 ? p1 : 120);
        const int gy = p / 11;
        const int gx = p - gy * 11;
        const float ys = y1 + (y2 - y1) * ((float)gy / 10.0f);
        const float xs = x1 + (x2 - x1) * ((float)gx / 10.0f);
        const float y0f = floorf(ys), x0f = floorf(xs);
        const float wy = ys - y0f, wxx = xs - x0f;
        const int y0i = (int)y0f, x0i = (int)x0f;
        const int y0c = min(max(y0i, 0), Hn - 1), y1c = min(max(y0i + 1, 0), Hn - 1);
        const int x0c = min(max(x0i, 0), Wn - 1), x1c = min(max(x0i + 1, 0), Wn - 1);
        o00[r] = y0c * Wn + x0c; o01[r] = y0c * Wn + x1c;
        o10[r] = y1c * Wn + x0c; o11[r] = y1c * Wn + x1c;
        w00[r] = (1.0f - wy) * (1.0f - wxx); w01[r] = (1.0f - wy) * wxx;
        w10[r] = wy * (1.0f - wxx);          w11[r] = wy * wxx;
    }
    const bool pool  = (lane < 25);
    const int  ph    = lane / 5;
    const int  pw    = lane - ph * 5;
    const int  pbase = (2 * ph) * 11 + 2 * pw;
    const float* base = feats + ((size_t)b * Cn + (size_t)wid * 64) * HWn;
    float*       op   = out + ((size_t)k * Cn + (size_t)wid * 64) * 25 + lane;
    for (int it = 0; it < 64; ++it) {
        const float* ff  = base + (size_t)it * HWn;
        float*       buf = smem[wid][it & 1];
        const float v0 = ff[o00[0]] * w00[0] + ff[o01[0]] * w01[0]
                       + ff[o10[0]] * w10[0] + ff[o11[0]] * w11[0];
        const float v1 = ff[o00[1]] * w00[1] + ff[o01[1]] * w01[1]
                       + ff[o10[1]] * w10[1] + ff[o11[1]] * w11[1];
        buf[lane] = v0;
        if (act1) buf[p1] = v1;
        if (pool) {
            float m =          buf[pbase +  0];
            m = fmaxf(m, buf[pbase +  1]);
            m = fmaxf(m, buf[pbase +  2]);
            m = fmaxf(m, buf[pbase + 11]);
            m = fmaxf(m, buf[pbase + 12]);
            m = fmaxf(m, buf[pbase + 13]);
            m = fmaxf(m, buf[pbase + 22]);
            m = fmaxf(m, buf[pbase + 23]);
            m = fmaxf(m, buf[pbase + 24]);
            op[it * 25] = m;
        }
    }
}

extern "C" void kernel_launch(void* const* d_in, const int* in_sizes, int n_in,
                              void* d_out, int out_size, void* d_ws, size_t ws_size,
                              hipStream_t stream) {
    const float* feats = (const float*)d_in[0];
    const float* rois  = (const float*)d_in[1];
    float*       out   = (float*)d_out;
    const int K = in_sizes[1] / 5;                                  // 2048
    const size_t need = (size_t)Bn * HWn * PAIRS * sizeof(unsigned int);  // 20.48 MB

    if (ws_size >= need) {
        unsigned int* nhwc = (unsigned int*)d_ws;
        dim3 tgrid((HWn + 63) / 64, PAIRS / 32, Bn);                // 157 x 4 x 4
        nchw_to_nhwc_f16<<<tgrid, 256, 0, stream>>>(feats, nhwc);
        roipool_u2<<<K, 128, 0, stream>>>((const __half2*)d_ws, rois, out);
    } else {
        roialign_pool_fallback<<<K, 256, 0, stream>>>(feats, rois, out);
    }
}

// Round 16
// 44.538 us; speedup vs baseline: 1.4182x; 1.4182x over previous
//
#include <hip/hip_runtime.h>
#include <hip/hip_fp16.h>

// RoIAlign dense (11x11 bilinear) + 3x3/s2 max pool -> [K=2048, C=256, 5, 5]
// features: [B=4, C=256, H=100, W=100] f32 (NCHW), rois: [K,5] f32
//
// Ladder: R5 42 main (f32 scalar) -> R8 ~34 (bf16 pairs) -> R14 ~31 main
// (f16 half2 packed lerps, scalar dword loads; total 42.5 BEST) ->
// R15 49 (uint2 loads -> VGPR-40 codegen collapse, 3rd repro).
// RULES (3x confirmed): scalar dword loads only; <=3 live half2[5] sets;
// no f32x2; no VGPR pins.
// R16: R14 math + R12's verified row-split to double grid-allowed waves/CU
// (16 -> 32): 256-thr block = 1 roi, wave = (rowgroup, half):
//   rg0: rows 0-4 -> ph0,ph1   rg1: rows 4-10 -> ph2,ph3,ph4 (row 4 dup)
// Stage = u32 half2 pairs (12.8 KB), per-ph writes (bounded regs), one
// barrier, branchless lo/hi unpack on coalesced copy-out (lines written once).

constexpr int Bn = 4, Cn = 256, Hn = 100, Wn = 100;
constexpr int HWn = Hn * Wn;
constexpr int PAIRS = Cn / 2;            // 128 channel pairs
constexpr float SCALE = 0.0625f;

__device__ __forceinline__ unsigned int hpack(float a, float b) {
    // RTNE f32->f16, pack (a -> low16, b -> high16)
    const __half2 h = __halves2half2(__float2half_rn(a), __float2half_rn(b));
    return *reinterpret_cast<const unsigned int*>(&h);
}
__device__ __forceinline__ __half2 u2h(unsigned int u) {
    return *reinterpret_cast<__half2*>(&u);
}
__device__ __forceinline__ unsigned int h2u(__half2 h) {
    return *reinterpret_cast<unsigned int*>(&h);
}
__device__ __forceinline__ __half2 hmax2(__half2 a, __half2 b) {
    // ROCm 7.2 has no __hmax2; emit the VOP3P packed max directly.
    unsigned int ur;
    asm("v_pk_max_f16 %0, %1, %2" : "=v"(ur) : "v"(h2u(a)), "v"(h2u(b)));
    return u2h(ur);
}

// ------- Kernel 1: NCHW f32 -> NHWC f16 (c, c+128)-pair (u32) transpose -------
// blockIdx.y covers 32 pairs: pairs p0..p0+31 = channels {p0+r, p0+r+128}.
__global__ __launch_bounds__(256)
void nchw_to_nhwc_f16(const float* __restrict__ in, unsigned int* __restrict__ out)
{
    __shared__ float tile[64][65];           // rows 0..31: ch p0+r; 32..63: ch p0+128+(r-32)
    const int s0 = blockIdx.x * 64;
    const int p0 = blockIdx.y * 32;          // pair-tile base (0,32,64,96)
    const int b  = blockIdx.z;
    const int t  = threadIdx.x;

    {   // load: thread -> tile row, 4 consecutive spatial (dwordx4)
        const int cl = t >> 4;               // 0..15
        const int s4 = (t & 15) * 4;         // 0..60
        const float* ip = in + (size_t)b * Cn * HWn + s0;
#pragma unroll
        for (int pass = 0; pass < 4; ++pass) {
            const int r  = pass * 16 + cl;   // tile row 0..63
            const int ch = (pass < 2) ? (p0 + r) : (p0 + 96 + r);  // +128 for hi half
            if (s0 + s4 + 3 < HWn) {
                const float4 v = *(const float4*)(ip + (size_t)ch * HWn + s4);
                tile[r][s4 + 0] = v.x; tile[r][s4 + 1] = v.y;
                tile[r][s4 + 2] = v.z; tile[r][s4 + 3] = v.w;
            } else {
#pragma unroll
                for (int i = 0; i < 4; ++i)
                    tile[r][s4 + i] = (s0 + s4 + i < HWn) ? ip[(size_t)ch * HWn + s4 + i] : 0.0f;
            }
        }
    }
    __syncthreads();
    {   // store: thread -> spatial s, uint2 = pairs (p0+li, p0+li+1)
        const int s = t >> 2;                // 0..63
        const int q = t & 3;
        if (s0 + s < HWn) {
            unsigned int* op = out + ((size_t)b * HWn + (s0 + s)) * PAIRS + p0;
#pragma unroll
            for (int i = 0; i < 4; ++i) {
                const int li = q * 2 + i * 8;            // even, 0..30
                uint2 v;
                v.x = hpack(tile[li    ][s], tile[li + 32][s]);  // pair p0+li
                v.y = hpack(tile[li + 1][s], tile[li + 33][s]);  // pair p0+li+1
                *(uint2*)(op + li) = v;
            }
        }
    }
}

// ------- Kernel 2: RoIAlign+pool, wave = (rowgroup, half), packed f16 -------
// 256-thr block = 1 roi. Lane handles pair pi = half*64+lane
// (channels pi lo, pi+128 hi). Scalar dword loads (R14-proven codegen).
__global__ __launch_bounds__(256)
void roipool_split16(const __half2* __restrict__ f, const float* __restrict__ rois,
                     float* __restrict__ out)
{
    __shared__ unsigned int stage[PAIRS * 25];   // 12.8 KB, half2 per (pair, ph*5+pw)
    const int tid  = threadIdx.x;
    const int wid  = tid >> 6;
    const int lane = tid & 63;
    const int half = wid & 1;                    // channel half
    const int rg   = wid >> 1;                   // row group (wave-uniform)
    const int k    = blockIdx.x;

    const float x1 = rois[k * 5 + 1] * SCALE;
    const float y1 = rois[k * 5 + 2] * SCALE;
    const float x2 = rois[k * 5 + 3] * SCALE;
    const float y2 = rois[k * 5 + 4] * SCALE;
    const int   b  = __builtin_amdgcn_readfirstlane((int)rois[k * 5 + 0]);

    const int pi = half * 64 + lane;             // pair index 0..127
    const __half2* fb = f + (size_t)b * HWn * PAIRS;

    // per-roi x-tap metadata: element offsets as SGPRs, weights as half2
    int     xo0[11], xo1[11];
    __half2 wxh[11];
#pragma unroll
    for (int j = 0; j < 11; ++j) {
        const float xs  = x1 + (x2 - x1) * ((float)j * 0.1f);
        const float x0f = floorf(xs);
        wxh[j] = __float2half2_rn(xs - x0f);     // weight from UNCLIPPED coord
        const int x0i = (int)x0f;
        xo0[j] = __builtin_amdgcn_readfirstlane(min(max(x0i,     0), Wn - 1)) * PAIRS;
        xo1[j] = __builtin_amdgcn_readfirstlane(min(max(x0i + 1, 0), Wn - 1)) * PAIRS;
    }

    // one dense sample row gy -> 5 x-window maxes, both channels packed f16
    auto dorow = [&](int gy, __half2 (&dst)[5]) {
        const float ys  = y1 + (y2 - y1) * ((float)gy * 0.1f);
        const float y0f = floorf(ys);
        const __half2 wyh = __float2half2_rn(ys - y0f);
        const int   y0i = (int)y0f;
        const int r0 = __builtin_amdgcn_readfirstlane(min(max(y0i,     0), Hn - 1));
        const int r1 = __builtin_amdgcn_readfirstlane(min(max(y0i + 1, 0), Hn - 1));
        const __half2* rp0 = fb + (size_t)(r0 * Wn) * PAIRS;   // uniform row ptrs
        const __half2* rp1 = fb + (size_t)(r1 * Wn) * PAIRS;
#pragma unroll
        for (int j = 0; j < 11; ++j) {
            const __half2 t00 = (rp0 + xo0[j])[pi];   // scalar dword loads
            const __half2 t01 = (rp0 + xo1[j])[pi];
            const __half2 t10 = (rp1 + xo0[j])[pi];
            const __half2 t11 = (rp1 + xo1[j])[pi];
            const __half2 X0 = __hfma2(wxh[j], __hsub2(t01, t00), t00);
            const __half2 X1 = __hfma2(wxh[j], __hsub2(t11, t10), t10);
            const __half2 s  = __hfma2(wyh,    __hsub2(X1,  X0),  X0);
            if (j == 0)      { dst[0] = s; }
            else if (j & 1)  { dst[j >> 1] = hmax2(dst[j >> 1], s); }
            else {
                dst[(j >> 1) - 1] = hmax2(dst[(j >> 1) - 1], s);
                if (j < 10) dst[j >> 1] = s;
            }
        }
    };

    // pooled ph row = max of three dense rows -> LDS stage (half2 packed)
    auto wrph = [&](int ph, const __half2 (&a)[5], const __half2 (&b_)[5], const __half2 (&c)[5]) {
        unsigned int* sp = &stage[pi * 25 + ph * 5];
#pragma unroll
        for (int pw = 0; pw < 5; ++pw)
            sp[pw] = h2u(hmax2(hmax2(a[pw], b_[pw]), c[pw]));
    };

    __half2 A[5], B[5], C[5];
    if (rg == 0) {                            // rows 0..4 -> ph0 (0,1,2), ph1 (2,3,4)
        dorow(0, A); dorow(1, B); dorow(2, C);
        wrph(0, A, B, C);
        dorow(3, A); dorow(4, B);
        wrph(1, C, A, B);
    } else {                                  // rows 4..10 -> ph2, ph3, ph4
        dorow(4, A); dorow(5, B); dorow(6, C);
        wrph(2, A, B, C);
        dorow(7, A); dorow(8, B);
        wrph(3, C, A, B);
        dorow(9, C); dorow(10, A);
        wrph(4, B, C, A);
    }

    __syncthreads();

    // coalesced copy-out: 6400 floats = 25 iters x 256 threads, branchless lo/hi
    float* ob = out + (size_t)k * (Cn * 25);
#pragma unroll
    for (int i = 0; i < 25; ++i) {
        const int idx = i * 256 + tid;        // 0..6399 = c*25 + (ph*5+pw)
        const int c   = idx / 25;             // const-div -> magic mul
        const int sub = idx - c * 25;
        const __half2 h = u2h(stage[(c & 127) * 25 + sub]);
        ob[idx] = (c < 128) ? __low2float(h) : __high2float(h);
    }
}

// ------------- Fallback (reads NCHW directly) if workspace too small -------------
__global__ __launch_bounds__(256)
void roialign_pool_fallback(const float* __restrict__ feats,
                            const float* __restrict__ rois,
                            float* __restrict__ out)
{
    __shared__ float smem[4][2][128];
    const int k    = blockIdx.x;
    const int tid  = threadIdx.x;
    const int wid  = tid >> 6;
    const int lane = tid & 63;

    const float x1 = rois[k * 5 + 1] * SCALE;
    const float y1 = rois[k * 5 + 2] * SCALE;
    const float x2 = rois[k * 5 + 3] * SCALE;
    const float y2 = rois[k * 5 + 4] * SCALE;
    const int   b  = (int)rois[k * 5 + 0];

    const int  p1   = 64 + lane;
    const bool act1 = (p1 < 121);
    int   o00[2], o01[2], o10[2], o11[2];
    float w00[2], w01[2], w10[2], w11[2];
#pragma unroll
    for (int r = 0; r < 2; ++r) {
        const int p  = (r == 0) ? lane : (act1 ? p1 : 120);
        const int gy = p / 11;
        const int gx = p - gy * 11;
        const float ys = y1 + (y2 - y1) * ((float)gy / 10.0f);
        const float xs = x1 + (x2 - x1) * ((float)gx / 10.0f);
        const float y0f = floorf(ys), x0f = floorf(xs);
        const float wy = ys - y0f, wxx = xs - x0f;
        const int y0i = (int)y0f, x0i = (int)x0f;
        const int y0c = min(max(y0i, 0), Hn - 1), y1c = min(max(y0i + 1, 0), Hn - 1);
        const int x0c = min(max(x0i, 0), Wn - 1), x1c = min(max(x0i + 1, 0), Wn - 1);
        o00[r] = y0c * Wn + x0c; o01[r] = y0c * Wn + x1c;
        o10[r] = y1c * Wn + x0c; o11[r] = y1c * Wn + x1c;
        w00[r] = (1.0f - wy) * (1.0f - wxx); w01[r] = (1.0f - wy) * wxx;
        w10[r] = wy * (1.0f - wxx);          w11[r] = wy * wxx;
    }
    const bool pool  = (lane < 25);
    const int  ph    = lane / 5;
    const int  pw    = lane - ph * 5;
    const int  pbase = (2 * ph) * 11 + 2 * pw;
    const float* base = feats + ((size_t)b * Cn + (size_t)wid * 64) * HWn;
    float*       op   = out + ((size_t)k * Cn + (size_t)wid * 64) * 25 + lane;
    for (int it = 0; it < 64; ++it) {
        const float* ff  = base + (size_t)it * HWn;
        float*       buf = smem[wid][it & 1];
        const float v0 = ff[o00[0]] * w00[0] + ff[o01[0]] * w01[0]
                       + ff[o10[0]] * w10[0] + ff[o11[0]] * w11[0];
        const float v1 = ff[o00[1]] * w00[1] + ff[o01[1]] * w01[1]
                       + ff[o10[1]] * w10[1] + ff[o11[1]] * w11[1];
        buf[lane] = v0;
        if (act1) buf[p1] = v1;
        if (pool) {
            float m =          buf[pbase +  0];
            m = fmaxf(m, buf[pbase +  1]);
            m = fmaxf(m, buf[pbase +  2]);
            m = fmaxf(m, buf[pbase + 11]);
            m = fmaxf(m, buf[pbase + 12]);
            m = fmaxf(m, buf[pbase + 13]);
            m = fmaxf(m, buf[pbase + 22]);
            m = fmaxf(m, buf[pbase + 23]);
            m = fmaxf(m, buf[pbase + 24]);
            op[it * 25] = m;
        }
    }
}

extern "C" void kernel_launch(void* const* d_in, const int* in_sizes, int n_in,
                              void* d_out, int out_size, void* d_ws, size_t ws_size,
                              hipStream_t stream) {
    const float* feats = (const float*)d_in[0];
    const float* rois  = (const float*)d_in[1];
    float*       out   = (float*)d_out;
    const int K = in_sizes[1] / 5;                                  // 2048
    const size_t need = (size_t)Bn * HWn * PAIRS * sizeof(unsigned int);  // 20.48 MB

    if (ws_size >= need) {
        unsigned int* nhwc = (unsigned int*)d_ws;
        dim3 tgrid((HWn + 63) / 64, PAIRS / 32, Bn);                // 157 x 4 x 4
        nchw_to_nhwc_f16<<<tgrid, 256, 0, stream>>>(feats, nhwc);
        roipool_split16<<<K, 256, 0, stream>>>((const __half2*)d_ws, rois, out);
    } else {
        roialign_pool_fallback<<<K, 256, 0, stream>>>(feats, rois, out);
    }
}

// Round 17
// 42.534 us; speedup vs baseline: 1.4850x; 1.0471x over previous
//
#include <hip/hip_runtime.h>
#include <hip/hip_fp16.h>

// RoIAlign dense (11x11 bilinear) + 3x3/s2 max pool -> [K=2048, C=256, 5, 5]
// features: [B=4, C=256, H=100, W=100] f32 (NCHW), rois: [K,5] f32
//
// FINAL (= R14, best measured 42.5us total: ~11us transpose + ~31us main).
// Ladder: R1 190 -> R2 45 -> R5 42 main -> R8 ~34 -> R14 ~31 main.
// Calibrations: R9 2x instr same lines = +20%; R16 +9% lines = +9%,
// 32 waves == 16 waves -> NOT latency-bound; time ~ L1-line count
// (968 loads x 4 lines ~= 26us/CU floor). Dedup levers all fail:
// branches serialize loads (R3/R4), vector-typed loads / f32x2 / VGPR pins
// collapse codegen (R10/R11/R15, VGPR 40 + VALUBusy ~20%).
// RULES: scalar dword loads only; <=3 live half2[5] sets; no f32x2;
// no VGPR pins; SGPR (readfirstlane) addressing; every output 64B line
// written exactly once by one instruction.

constexpr int Bn = 4, Cn = 256, Hn = 100, Wn = 100;
constexpr int HWn = Hn * Wn;
constexpr int PAIRS = Cn / 2;            // 128 channel pairs
constexpr float SCALE = 0.0625f;

__device__ __forceinline__ unsigned int hpack(float a, float b) {
    // RTNE f32->f16, pack (a -> low16, b -> high16)
    const __half2 h = __halves2half2(__float2half_rn(a), __float2half_rn(b));
    return *reinterpret_cast<const unsigned int*>(&h);
}
__device__ __forceinline__ __half2 u2h(unsigned int u) {
    return *reinterpret_cast<__half2*>(&u);
}
__device__ __forceinline__ unsigned int h2u(__half2 h) {
    return *reinterpret_cast<unsigned int*>(&h);
}
__device__ __forceinline__ __half2 hmax2(__half2 a, __half2 b) {
    // ROCm 7.2 has no __hmax2; emit the VOP3P packed max directly.
    unsigned int ur;
    asm("v_pk_max_f16 %0, %1, %2" : "=v"(ur) : "v"(h2u(a)), "v"(h2u(b)));
    return u2h(ur);
}

// ------- Kernel 1: NCHW f32 -> NHWC f16 (c, c+128)-pair (u32) transpose -------
// blockIdx.y covers 32 pairs: pairs p0..p0+31 = channels {p0+r, p0+r+128}.
__global__ __launch_bounds__(256)
void nchw_to_nhwc_f16(const float* __restrict__ in, unsigned int* __restrict__ out)
{
    __shared__ float tile[64][65];           // rows 0..31: ch p0+r; 32..63: ch p0+128+(r-32)
    const int s0 = blockIdx.x * 64;
    const int p0 = blockIdx.y * 32;          // pair-tile base (0,32,64,96)
    const int b  = blockIdx.z;
    const int t  = threadIdx.x;

    {   // load: thread -> tile row, 4 consecutive spatial (dwordx4)
        const int cl = t >> 4;               // 0..15
        const int s4 = (t & 15) * 4;         // 0..60
        const float* ip = in + (size_t)b * Cn * HWn + s0;
#pragma unroll
        for (int pass = 0; pass < 4; ++pass) {
            const int r  = pass * 16 + cl;   // tile row 0..63
            const int ch = (pass < 2) ? (p0 + r) : (p0 + 96 + r);  // +128 for hi half
            if (s0 + s4 + 3 < HWn) {
                const float4 v = *(const float4*)(ip + (size_t)ch * HWn + s4);
                tile[r][s4 + 0] = v.x; tile[r][s4 + 1] = v.y;
                tile[r][s4 + 2] = v.z; tile[r][s4 + 3] = v.w;
            } else {
#pragma unroll
                for (int i = 0; i < 4; ++i)
                    tile[r][s4 + i] = (s0 + s4 + i < HWn) ? ip[(size_t)ch * HWn + s4 + i] : 0.0f;
            }
        }
    }
    __syncthreads();
    {   // store: thread -> spatial s, uint2 = pairs (p0+li, p0+li+1)
        const int s = t >> 2;                // 0..63
        const int q = t & 3;
        if (s0 + s < HWn) {
            unsigned int* op = out + ((size_t)b * HWn + (s0 + s)) * PAIRS + p0;
#pragma unroll
            for (int i = 0; i < 4; ++i) {
                const int li = q * 2 + i * 8;            // even, 0..30
                uint2 v;
                v.x = hpack(tile[li    ][s], tile[li + 32][s]);  // pair p0+li
                v.y = hpack(tile[li + 1][s], tile[li + 33][s]);  // pair p0+li+1
                *(uint2*)(op + li) = v;
            }
        }
    }
}

// ------- Kernel 2: RoIAlign+pool, lane = channel pair, packed f16 math -------
// 128-thread block = 1 roi; wave wid = channel half (pairs wid*64..+63 =
// channels wid*64..+63 lo, +128 hi). Stage 1600 floats/wave = 12.8 KB.
__global__ __launch_bounds__(128)
void roipool_half(const __half2* __restrict__ f, const float* __restrict__ rois,
                  float* __restrict__ out)
{
    __shared__ float stage[2][1600];          // [wave][64ch x 25], 12.8 KB
    const int tid  = threadIdx.x;
    const int wid  = tid >> 6;                // channel half
    const int lane = tid & 63;
    const int k    = blockIdx.x;

    const float x1 = rois[k * 5 + 1] * SCALE;
    const float y1 = rois[k * 5 + 2] * SCALE;
    const float x2 = rois[k * 5 + 3] * SCALE;
    const float y2 = rois[k * 5 + 4] * SCALE;
    const int   b  = __builtin_amdgcn_readfirstlane((int)rois[k * 5 + 0]);

    const int pi = wid * 64 + lane;           // pair index 0..127
    const __half2* fb = f + (size_t)b * HWn * PAIRS;

    // per-roi x-tap metadata: element offsets as SGPRs, weights as half2
    int     xo0[11], xo1[11];
    __half2 wxh[11];
#pragma unroll
    for (int j = 0; j < 11; ++j) {
        const float xs  = x1 + (x2 - x1) * ((float)j * 0.1f);
        const float x0f = floorf(xs);
        wxh[j] = __float2half2_rn(xs - x0f);  // weight from UNCLIPPED coord
        const int x0i = (int)x0f;
        xo0[j] = __builtin_amdgcn_readfirstlane(min(max(x0i,     0), Wn - 1)) * PAIRS;
        xo1[j] = __builtin_amdgcn_readfirstlane(min(max(x0i + 1, 0), Wn - 1)) * PAIRS;
    }

    // one dense sample row gy -> 5 x-window maxes, both channels packed f16
    auto dorow = [&](int gy, __half2 (&dst)[5]) {
        const float ys  = y1 + (y2 - y1) * ((float)gy * 0.1f);
        const float y0f = floorf(ys);
        const __half2 wyh = __float2half2_rn(ys - y0f);
        const int   y0i = (int)y0f;
        const int r0 = __builtin_amdgcn_readfirstlane(min(max(y0i,     0), Hn - 1));
        const int r1 = __builtin_amdgcn_readfirstlane(min(max(y0i + 1, 0), Hn - 1));
        const __half2* rp0 = fb + (size_t)(r0 * Wn) * PAIRS;   // uniform row ptrs
        const __half2* rp1 = fb + (size_t)(r1 * Wn) * PAIRS;
#pragma unroll
        for (int j = 0; j < 11; ++j) {
            const __half2 t00 = (rp0 + xo0[j])[pi];   // scalar dword loads
            const __half2 t01 = (rp0 + xo1[j])[pi];
            const __half2 t10 = (rp1 + xo0[j])[pi];
            const __half2 t11 = (rp1 + xo1[j])[pi];
            const __half2 X0 = __hfma2(wxh[j], __hsub2(t01, t00), t00);
            const __half2 X1 = __hfma2(wxh[j], __hsub2(t11, t10), t10);
            const __half2 s  = __hfma2(wyh,    __hsub2(X1,  X0),  X0);
            if (j == 0)      { dst[0] = s; }
            else if (j & 1)  { dst[j >> 1] = hmax2(dst[j >> 1], s); }
            else {
                dst[(j >> 1) - 1] = hmax2(dst[(j >> 1) - 1], s);
                if (j < 10) dst[j >> 1] = s;
            }
        }
    };

    __half2 prev[5], o2[25];
    dorow(0, prev);
#pragma unroll
    for (int ph = 0; ph < 5; ++ph) {
        __half2 tt[5], nxt[5];
        dorow(2 * ph + 1, tt);
        dorow(2 * ph + 2, nxt);
#pragma unroll
        for (int pw = 0; pw < 5; ++pw) {
            o2[ph * 5 + pw] = hmax2(hmax2(prev[pw], tt[pw]), nxt[pw]);
            prev[pw] = nxt[pw];
        }
    }

    float* stw = stage[wid];
    float* stl = &stw[lane * 25];

    // phase A: lo channels (wid*64..+63) -> contiguous 1600-float out block
#pragma unroll
    for (int p = 0; p < 25; ++p)
        stl[p] = __low2float(o2[p]);
    asm volatile("" ::: "memory");            // same-wave LDS in-order; pin ordering
    float* obl = out + (size_t)k * (Cn * 25) + (size_t)wid * 1600;
#pragma unroll
    for (int i = 0; i < 25; ++i)
        obl[i * 64 + lane] = stw[i * 64 + lane];

    // phase B: hi channels (+128) -> out block at +3200 floats
    asm volatile("" ::: "memory");
#pragma unroll
    for (int p = 0; p < 25; ++p)
        stl[p] = __high2float(o2[p]);
    asm volatile("" ::: "memory");
    float* obh = obl + 3200;
#pragma unroll
    for (int i = 0; i < 25; ++i)
        obh[i * 64 + lane] = stw[i * 64 + lane];
}

// ------------- Fallback (reads NCHW directly) if workspace too small -------------
__global__ __launch_bounds__(256)
void roialign_pool_fallback(const float* __restrict__ feats,
                            const float* __restrict__ rois,
                            float* __restrict__ out)
{
    __shared__ float smem[4][2][128];
    const int k    = blockIdx.x;
    const int tid  = threadIdx.x;
    const int wid  = tid >> 6;
    const int lane = tid & 63;

    const float x1 = rois[k * 5 + 1] * SCALE;
    const float y1 = rois[k * 5 + 2] * SCALE;
    const float x2 = rois[k * 5 + 3] * SCALE;
    const float y2 = rois[k * 5 + 4] * SCALE;
    const int   b  = (int)rois[k * 5 + 0];

    const int  p1   = 64 + lane;
    const bool act1 = (p1 < 121);
    int   o00[2], o01[2], o10[2], o11[2];
    float w00[2], w01[2], w10[2], w11[2];
#pragma unroll
    for (int r = 0; r < 2; ++r) {
        const int p  = (r == 0) ? lane : (act1 ? p1 : 120);
        const int gy = p / 11;
        const int gx = p - gy * 11;
        const float ys = y1 + (y2 - y1) * ((float)gy / 10.0f);
        const float xs = x1 + (x2 - x1) * ((float)gx / 10.0f);
        const float y0f = floorf(ys), x0f = floorf(xs);
        const float wy = ys - y0f, wxx = xs - x0f;
        const int y0i = (int)y0f, x0i = (int)x0f;
        const int y0c = min(max(y0i, 0), Hn - 1), y1c = min(max(y0i + 1, 0), Hn - 1);
        const int x0c = min(max(x0i, 0), Wn - 1), x1c = min(max(x0i + 1, 0), Wn - 1);
        o00[r] = y0c * Wn + x0c; o01[r] = y0c * Wn + x1c;
        o10[r] = y1c * Wn + x0c; o11[r] = y1c * Wn + x1c;
        w00[r] = (1.0f - wy) * (1.0f - wxx); w01[r] = (1.0f - wy) * wxx;
        w10[r] = wy * (1.0f - wxx);          w11[r] = wy * wxx;
    }
    const bool pool  = (lane < 25);
    const int  ph    = lane / 5;
    const int  pw    = lane - ph * 5;
    const int  pbase = (2 * ph) * 11 + 2 * pw;
    const float* base = feats + ((size_t)b * Cn + (size_t)wid * 64) * HWn;
    float*       op   = out + ((size_t)k * Cn + (size_t)wid * 64) * 25 + lane;
    for (int it = 0; it < 64; ++it) {
        const float* ff  = base + (size_t)it * HWn;
        float*       buf = smem[wid][it & 1];
        const float v0 = ff[o00[0]] * w00[0] + ff[o01[0]] * w01[0]
                       + ff[o10[0]] * w10[0] + ff[o11[0]] * w11[0];
        const float v1 = ff[o00[1]] * w00[1] + ff[o01[1]] * w01[1]
                       + ff[o10[1]] * w10[1] + ff[o11[1]] * w11[1];
        buf[lane] = v0;
        if (act1) buf[p1] = v1;
        if (pool) {
            float m =          buf[pbase +  0];
            m = fmaxf(m, buf[pbase +  1]);
            m = fmaxf(m, buf[pbase +  2]);
            m = fmaxf(m, buf[pbase + 11]);
            m = fmaxf(m, buf[pbase + 12]);
            m = fmaxf(m, buf[pbase + 13]);
            m = fmaxf(m, buf[pbase + 22]);
            m = fmaxf(m, buf[pbase + 23]);
            m = fmaxf(m, buf[pbase + 24]);
            op[it * 25] = m;
        }
    }
}

extern "C" void kernel_launch(void* const* d_in, const int* in_sizes, int n_in,
                              void* d_out, int out_size, void* d_ws, size_t ws_size,
                              hipStream_t stream) {
    const float* feats = (const float*)d_in[0];
    const float* rois  = (const float*)d_in[1];
    float*       out   = (float*)d_out;
    const int K = in_sizes[1] / 5;                                  // 2048
    const size_t need = (size_t)Bn * HWn * PAIRS * sizeof(unsigned int);  // 20.48 MB

    if (ws_size >= need) {
        unsigned int* nhwc = (unsigned int*)d_ws;
        dim3 tgrid((HWn + 63) / 64, PAIRS / 32, Bn);                // 157 x 4 x 4
        nchw_to_nhwc_f16<<<tgrid, 256, 0, stream>>>(feats, nhwc);
        roipool_half<<<K, 128, 0, stream>>>((const __half2*)d_ws, rois, out);
    } else {
        roialign_pool_fallback<<<K, 256, 0, stream>>>(feats, rois, out);
    }
}